// Round 8
// baseline (383.842 us; speedup 1.0000x reference)
//
#include <hip/hip_runtime.h>
#include <hip/hip_bf16.h>
#include <hip/hip_fp16.h>

// CompressedFP8Linear: out[128,8192] = x[128,8192] @ (w*scale)[8192,8192]^T + bias
//
// R15 journal:
//  - R14 post-mortem: total 380 (best). Actionable 115 = xprep 6 + gemm ~105.
//    2KB-run reshape worked (141 -> ~105): run length IS the lever. Remaining
//    known defects: (1) staging instrs scatter 64 lanes over 64 lines @16B
//    each (8x request amplification at L1/L2); (2) 4M atomicAdd dwords in the
//    epilogue (16MB RMW traffic, R8-measured) contending with the w stream.
//  - R15: same proven 32n x 128m x 2048k structure + compute loop, with:
//      * wave-coalesced staging: one instr = one row's 1KB contiguous
//        (lane*16B), cvt to bf16x4, ds_write_b64 into the SAME XOR'd LDS
//        image as R14 (compute loop untouched).
//      * no atomics: raw partials to ws (plain stores), new reduce kernel
//        sums 4 kz partials, applies scale+bias (probe moved there), writes
//        out. No memset in this path. gemm no longer reads c1/c2.
//  - Fill floor ~265us unconditional. Predict actionable 65-80, total 330-350.
//  - Falsifier: total >= 370 -> staging/atomics exonerated; ablate next.

namespace {
constexpr int NN = 8192;
constexpr int KK = 8192;
constexpr int KSPLIT = 4;
constexpr int KPB = KK / KSPLIT;     // 2048 k per block
constexpr int BKT = 512;             // k per staged w tile
constexpr int NIT = KPB / BKT;       // 4 tiles

constexpr size_t XOFF = 0;                         // 2 MB x_r (bf16 frag order)
constexpr size_t POFF = (size_t)128 * KK * 2;      // partials start at 2 MB
constexpr size_t PSZ  = (size_t)128 * NN * 4;      // 4 MB per kz partial
constexpr size_t WS_NEED = POFF + (size_t)KSPLIT * PSZ;   // 18 MB

typedef __attribute__((ext_vector_type(8))) short bf16x8;
typedef __attribute__((ext_vector_type(4))) float f32x4;

__device__ __forceinline__ bf16x8 pack8(float4 a, float4 b) {
    union { __hip_bfloat16 h[8]; bf16x8 v; } p;
    p.h[0] = __float2bfloat16(a.x); p.h[1] = __float2bfloat16(a.y);
    p.h[2] = __float2bfloat16(a.z); p.h[3] = __float2bfloat16(a.w);
    p.h[4] = __float2bfloat16(b.x); p.h[5] = __float2bfloat16(b.y);
    p.h[6] = __float2bfloat16(b.z); p.h[7] = __float2bfloat16(b.w);
    return p.v;
}

__device__ __forceinline__ void gload_lds16(const void* g, void* l) {
    __builtin_amdgcn_global_load_lds(
        (const __attribute__((address_space(1))) unsigned int*)g,
        (__attribute__((address_space(3))) unsigned int*)l,
        16, 0, 0);
}
}

#define RAW_BARRIER() asm volatile("s_barrier" ::: "memory")
#define VMWAIT(N_)    asm volatile("s_waitcnt vmcnt(" #N_ ")" ::: "memory")

// ---------------- x-prep (R7-verified swizzle): x fp32 -> frag-order bf16 ----
// uint4 index ((s*8 + t)*64 + l) holds A[m=16t+(l&15)][k=32s+(l>>4)*8+j], j=0..7
__global__ __launch_bounds__(256)
void cfp8_xprep(const float* __restrict__ x, unsigned char* __restrict__ ws)
{
    const int g = blockIdx.x * 256 + threadIdx.x;   // [0, 131072)
    const float4* src = (const float4*)x + (size_t)g * 2;
    float4 a = src[0], b = src[1];
    const int m  = g >> 10;
    const int kg = g & 1023;
    const int s  = kg >> 2;
    const int r8 = kg & 3;
    const int t  = m >> 4;
    const int lm = m & 15;
    const int l  = r8 * 16 + lm;
    union { __hip_bfloat16 h[8]; uint4 u; } p;
    p.h[0] = __float2bfloat16(a.x); p.h[1] = __float2bfloat16(a.y);
    p.h[2] = __float2bfloat16(a.z); p.h[3] = __float2bfloat16(a.w);
    p.h[4] = __float2bfloat16(b.x); p.h[5] = __float2bfloat16(b.y);
    p.h[6] = __float2bfloat16(b.z); p.h[7] = __float2bfloat16(b.w);
    ((uint4*)(ws + XOFF))[(size_t)(s * 8 + t) * 64 + l] = p.u;
}

// ---------------- gemm: 32n x 128m, coalesced staging, partial stores ----------
__global__ __launch_bounds__(256, 4)
void cfp8_gemm_r15(const float* __restrict__ w, const unsigned char* __restrict__ ws,
                   float* __restrict__ part)
{
    // single 32-row x 512-k bf16 tile = 32 KB -> 4 blocks/CU
    __shared__ __align__(16) __hip_bfloat16 lw[32 * BKT];

    const int tid  = threadIdx.x;
    const int lane = tid & 63;
    const int wid  = tid >> 6;
    const int l16  = lane & 15;
    const int quad = lane >> 4;
    const int bid  = blockIdx.x;
    const int kz   = bid & 3;             // XCD-affine x slice
    const int n0   = (bid >> 2) * 32;
    const size_t kbase = (size_t)kz * KPB;

    const uint4* xr = (const uint4*)(ws + XOFF);

    f32x4 acc[2][2];
#pragma unroll
    for (int i = 0; i < 2; ++i)
#pragma unroll
        for (int j = 0; j < 2; ++j) acc[i][j] = (f32x4){0.f, 0.f, 0.f, 0.f};

    for (int c = 0; c < NIT; ++c) {
        if (c) __syncthreads();           // previous tile's readers done

        // ---- stage tile c: wave owns rows wid*8..+7; per row two 1KB
        //      wave-contiguous loads (lane*16B), bf16x4 -> ds_write_b64 ----
#pragma unroll 1
        for (int rg = 0; rg < 2; ++rg) {
            float4 v[4][2];
#pragma unroll
            for (int rr = 0; rr < 4; ++rr) {
                const int r = wid * 8 + rg * 4 + rr;
                const float* src = w + (size_t)(n0 + r) * KK + kbase + c * BKT;
                v[rr][0] = *(const float4*)(src + lane * 4);        // floats [l*4)
                v[rr][1] = *(const float4*)(src + 256 + lane * 4);  // second KB
            }
#pragma unroll
            for (int rr = 0; rr < 4; ++rr) {
                const int r = wid * 8 + rg * 4 + rr;
#pragma unroll
                for (int i = 0; i < 2; ++i) {
                    const int g = i * 32 + (lane >> 1);   // 16B chunk idx 0..63
                    union { __hip_bfloat16 h[4]; uint2 u; } p;
                    p.h[0] = __float2bfloat16(v[rr][i].x);
                    p.h[1] = __float2bfloat16(v[rr][i].y);
                    p.h[2] = __float2bfloat16(v[rr][i].z);
                    p.h[3] = __float2bfloat16(v[rr][i].w);
                    *(uint2*)((char*)lw + r * 1024 +
                              ((g ^ (r & 7)) << 4) + (lane & 1) * 8) = p.u;
                }
            }
        }
        __syncthreads();

        // ---- compute: 16 k-steps (identical to R14-verified loop) ----
        const int ksg0 = kz * 64 + c * 16;
#pragma unroll 4
        for (int ks = 0; ks < 16; ++ks) {
            bf16x8 af[2], bf[2];
#pragma unroll
            for (int i = 0; i < 2; ++i) {
                uint4 u = xr[(size_t)((ksg0 + ks) * 8 + wid * 2 + i) * 64 + lane];
                af[i] = *(bf16x8*)&u;
            }
#pragma unroll
            for (int j = 0; j < 2; ++j) {
                const int row_ = j * 16 + l16;
                const int kc   = ks * 4 + quad;
                bf[j] = *(const bf16x8*)((const char*)lw + row_ * 1024 +
                                         ((kc ^ (row_ & 7)) << 4));
            }
#pragma unroll
            for (int i = 0; i < 2; ++i)
#pragma unroll
                for (int j = 0; j < 2; ++j)
                    acc[i][j] = __builtin_amdgcn_mfma_f32_16x16x32_bf16(
                        af[i], bf[j], acc[i][j], 0, 0, 0);
        }
    }

    // ---- epilogue: raw partial stores (no atomics, no scale/bias here) ----
    float* pk = part + (size_t)kz * (PSZ / 4);
#pragma unroll
    for (int j = 0; j < 2; ++j) {
        const int col = n0 + j * 16 + l16;
#pragma unroll
        for (int i = 0; i < 2; ++i) {
            const int mb = wid * 32 + i * 16 + quad * 4;
#pragma unroll
            for (int r = 0; r < 4; ++r)
                pk[(size_t)(mb + r) * NN + col] = acc[i][j][r];
        }
    }
}

// ---------------- reduce: sum 4 kz partials, scale+bias, write out ----------
__global__ __launch_bounds__(256)
void cfp8_reduce(const float* __restrict__ part,
                 const float* __restrict__ c1, const float* __restrict__ c2,
                 float* __restrict__ out)
{
    __shared__ int s_c1s, s_kind;
    const int tid = threadIdx.x;
    if (tid < 64) {
        float v = c1[tid * 64];
        unsigned long long b = __ballot((v > 1e-4f) && (v < 0.5f));
        int c1s = (b == ~0ull) ? 1 : 0;
        const void* bp = c1s ? (const void*)c2 : (const void*)c1;
        float vf = __half2float(((const __half*)bp)[tid * 64]);
        unsigned long long bf_ = __ballot((vf < 0.5f) && (vf > -0.5f));
        float vb = __bfloat162float(((const __hip_bfloat16*)bp)[tid * 64]);
        unsigned long long bb = __ballot((vb < 0.5f) && (vb > -0.5f));
        if (tid == 0) {
            s_c1s  = c1s;
            s_kind = (bf_ == ~0ull) ? 0 : ((bb == ~0ull) ? 1 : 2);
        }
    }
    __syncthreads();

    const int g = blockIdx.x * 256 + tid;           // [0, 262144) float4 idx
    const float4* p4 = (const float4*)part;
    float4 s = p4[g];
#pragma unroll
    for (int kz = 1; kz < KSPLIT; ++kz) {
        float4 p = p4[(size_t)kz * (PSZ / 16) + g];
        s.x += p.x; s.y += p.y; s.z += p.z; s.w += p.w;
    }

    const int n = (g & 2047) * 4;                   // col of first element
    const float* scalep = s_c1s ? c1 : c2;
    const void*  biasp  = s_c1s ? (const void*)c2 : (const void*)c1;
    float4 sc = *(const float4*)(scalep + n);
    float bs[4];
#pragma unroll
    for (int r = 0; r < 4; ++r) {
        if (s_kind == 0)      bs[r] = __half2float(((const __half*)biasp)[n + r]);
        else if (s_kind == 1) bs[r] = __bfloat162float(((const __hip_bfloat16*)biasp)[n + r]);
        else                  bs[r] = ((const float*)biasp)[n + r];
    }
    float4 o;
    o.x = s.x * sc.x + bs[0];
    o.y = s.y * sc.y + bs[1];
    o.z = s.z * sc.z + bs[2];
    o.w = s.w * sc.w + bs[3];
    ((float4*)out)[g] = o;
}

// ---------------- fallback: R12 (proven pass) if ws too small ----------------
__global__ __launch_bounds__(256, 1)
void cfp8_gemm_r12(const float* __restrict__ x, const float* __restrict__ w,
                   const float* __restrict__ c1, const float* __restrict__ c2,
                   float* __restrict__ out)
{
    constexpr int BKF = 32;
    constexpr int NITF = KPB / BKF;
    __shared__ __align__(16) float ldsA[4][128 * BKF];
    __shared__ __align__(16) float ldsB[4][128 * BKF];
    __shared__ int s_c1s, s_kind;

    const int tid  = threadIdx.x;
    const int lane = tid & 63;
    const int wid  = tid >> 6;
    const int l16  = lane & 15;
    const int quad = lane >> 4;
    const int wr   = wid >> 1;
    const int wc   = wid & 1;
    const int bid  = blockIdx.x;
    const int kz   = bid & 3;
    const int nb0  = (bid >> 2) * 128;
    const size_t kbase = (size_t)kz * KPB;

    if (tid < 64) {
        float v = c1[tid * 64];
        unsigned long long b = __ballot((v > 1e-4f) && (v < 0.5f));
        int c1s = (b == ~0ull) ? 1 : 0;
        const void* bp = c1s ? (const void*)c2 : (const void*)c1;
        float vf = __half2float(((const __half*)bp)[tid * 64]);
        unsigned long long bf_ = __ballot((vf < 0.5f) && (vf > -0.5f));
        float vb = __bfloat162float(((const __hip_bfloat16*)bp)[tid * 64]);
        unsigned long long bb = __ballot((vb < 0.5f) && (vb > -0.5f));
        if (tid == 0) {
            s_c1s = c1s;
            s_kind = (bf_ == ~0ull) ? 0 : ((bb == ~0ull) ? 1 : 2);
        }
    }
    __syncthreads();

    unsigned off[4];
#pragma unroll
    for (int j = 0; j < 4; ++j) {
        const int q   = (wid * 4 + j) * 64 + lane;
        const int row = q >> 3;
        const int c8  = q & 7;
        const int swz = c8 ^ (row & 7);
        off[j] = (unsigned)row * (KK * 4) + (unsigned)swz * 16;
    }
    const char* xsrc = (const char*)(x + kbase);
    const char* wsrc = (const char*)(w + (size_t)nb0 * KK + kbase);

#define STAGE(slot_, c_)                                                       \
    {                                                                          \
        const size_t kb_ = (size_t)(c_) * (BKF * 4);                           \
        _Pragma("unroll")                                                      \
        for (int j = 0; j < 4; ++j) {                                          \
            gload_lds16(xsrc + kb_ + off[j],                                   \
                        (char*)&ldsA[slot_][0] + (wid * 4 + j) * 1024);        \
            gload_lds16(wsrc + kb_ + off[j],                                   \
                        (char*)&ldsB[slot_][0] + (wid * 4 + j) * 1024);        \
        }                                                                      \
    }
#define LOADFRAG(dst_, base_, rb_)                                             \
    {                                                                          \
        const int row_ = (rb_) + l16;                                          \
        const int sw_  = row_ & 7;                                             \
        float4 a0_ = *(const float4*)&(base_)[(row_ * 8 + ((quad * 2) ^ sw_)) * 4];     \
        float4 a1_ = *(const float4*)&(base_)[(row_ * 8 + ((quad * 2 + 1) ^ sw_)) * 4]; \
        dst_ = pack8(a0_, a1_);                                                \
    }
#define COMPUTE(slot_)                                                         \
    {                                                                          \
        const float* la_ = &ldsA[slot_][0];                                    \
        const float* lb_ = &ldsB[slot_][0];                                    \
        bf16x8 af_[4], bf_[4];                                                 \
        _Pragma("unroll")                                                      \
        for (int i = 0; i < 4; ++i) LOADFRAG(af_[i], la_, wr * 64 + i * 16)    \
        _Pragma("unroll")                                                      \
        for (int j = 0; j < 4; ++j) LOADFRAG(bf_[j], lb_, wc * 64 + j * 16)    \
        _Pragma("unroll")                                                      \
        for (int i = 0; i < 4; ++i)                                            \
            _Pragma("unroll")                                                  \
            for (int j = 0; j < 4; ++j)                                        \
                acc[i][j] = __builtin_amdgcn_mfma_f32_16x16x32_bf16(           \
                    af_[i], bf_[j], acc[i][j], 0, 0, 0);                       \
    }

    f32x4 acc[4][4];
#pragma unroll
    for (int i = 0; i < 4; ++i)
#pragma unroll
        for (int j = 0; j < 4; ++j) acc[i][j] = (f32x4){0.f, 0.f, 0.f, 0.f};

    STAGE(0, 0)
    STAGE(1, 1)
    STAGE(2, 2)
    for (int c = 0; c < NITF - 3; ++c) {
        VMWAIT(16);
        RAW_BARRIER();
        STAGE((c + 3) & 3, c + 3)
        COMPUTE(c & 3)
    }
    VMWAIT(16); RAW_BARRIER(); COMPUTE((NITF - 3) & 3)
    VMWAIT(8);  RAW_BARRIER(); COMPUTE((NITF - 2) & 3)
    VMWAIT(0);  RAW_BARRIER(); COMPUTE((NITF - 1) & 3)
#undef STAGE
#undef LOADFRAG
#undef COMPUTE

    const float* scalep = s_c1s ? c1 : c2;
    const void*  biasp  = s_c1s ? (const void*)c2 : (const void*)c1;
#pragma unroll
    for (int j = 0; j < 4; ++j) {
        const int col = nb0 + wc * 64 + j * 16 + l16;
        const float scj = scalep[col];
        float bsj = 0.0f;
        if (kz == 0) {
            if (s_kind == 0)      bsj = __half2float(((const __half*)biasp)[col]);
            else if (s_kind == 1) bsj = __bfloat162float(((const __hip_bfloat16*)biasp)[col]);
            else                  bsj = ((const float*)biasp)[col];
        }
#pragma unroll
        for (int i = 0; i < 4; ++i) {
            const int rb = wr * 64 + i * 16 + quad * 4;
#pragma unroll
            for (int r = 0; r < 4; ++r)
                atomicAdd(out + (size_t)(rb + r) * NN + col,
                          acc[i][j][r] * scj + bsj);
        }
    }
}

extern "C" void kernel_launch(void* const* d_in, const int* in_sizes, int n_in,
                              void* d_out, int out_size, void* d_ws, size_t ws_size,
                              hipStream_t stream) {
    // Size-RANK input ID (R4-verified): largest = weight, 2nd = x,
    // remaining two = {scale, bias} (disambiguated on device).
    int iw = 0;
    for (int i = 1; i < n_in; ++i) if (in_sizes[i] > in_sizes[iw]) iw = i;
    int ix = -1;
    for (int i = 0; i < n_in; ++i)
        if (i != iw && (ix < 0 || in_sizes[i] > in_sizes[ix])) ix = i;
    const float* c1 = nullptr;
    const float* c2 = nullptr;
    for (int i = 0; i < n_in; ++i) {
        if (i == iw || i == ix) continue;
        if (!c1) c1 = (const float*)d_in[i];
        else     c2 = (const float*)d_in[i];
    }
    const float* w = (const float*)d_in[iw];
    const float* x = (const float*)d_in[ix];
    float* out = (float*)d_out;

    if (d_ws != nullptr && ws_size >= WS_NEED) {
        unsigned char* ws = (unsigned char*)d_ws;
        float* part = (float*)(ws + POFF);
        cfp8_xprep<<<dim3(512), dim3(256), 0, stream>>>(x, ws);
        cfp8_gemm_r15<<<dim3(256 * KSPLIT), dim3(256), 0, stream>>>(w, ws, part);
        cfp8_reduce<<<dim3(1024), dim3(256), 0, stream>>>(part, c1, c2, out);
    } else {
        hipMemsetAsync(d_out, 0, (size_t)out_size * sizeof(float), stream);
        cfp8_gemm_r12<<<dim3(64 * KSPLIT), dim3(256), 0, stream>>>(x, w, c1, c2, out);
    }
}